// Round 1
// baseline (211.820 us; speedup 1.0000x reference)
//
#include <hip/hip_runtime.h>
#include <math.h>

#define C_  1204
#define C4_ 301   // C_/4 float4s per row (1204 % 4 == 0, rows 16B-aligned)

__device__ __forceinline__ float waveReduceMax(float v){
    #pragma unroll
    for (int o = 32; o > 0; o >>= 1) v = fmaxf(v, __shfl_xor(v, o, 64));
    return v;
}
__device__ __forceinline__ float waveReduceSum(float v){
    #pragma unroll
    for (int o = 32; o > 0; o >>= 1) v += __shfl_xor(v, o, 64);
    return v;
}

// ---- zero the accumulators the later kernels need (ws is poisoned 0xAA) ----
__global__ void k_init(float* posg, int* counts, float* tcol, float* scal){
    int i = blockIdx.x * blockDim.x + threadIdx.x;
    if (i < C_){ posg[i] = 0.f; counts[i] = 0; tcol[i] = 0.f; }
    if (i < 8) scal[i] = 0.f;
}

// ---- per-row max and sumexp; one wave per row, float4 loads ----
__global__ void k_rowstats(const float* __restrict__ cs,
                           float* __restrict__ rowmax, float* __restrict__ rowsum){
    int lane = threadIdx.x & 63;
    int n = blockIdx.x * 4 + (threadIdx.x >> 6);
    const float4* row = reinterpret_cast<const float4*>(cs + (size_t)n * C_);
    float4 v[5]; int cnt = 0;
    float m = -3.402823466e38f;
    for (int idx = lane; idx < C4_; idx += 64){
        float4 x = row[idx];
        v[cnt++] = x;
        m = fmaxf(m, fmaxf(fmaxf(x.x, x.y), fmaxf(x.z, x.w)));
    }
    m = waveReduceMax(m);
    float s = 0.f;
    for (int k = 0; k < cnt; ++k)
        s += __expf(v[k].x - m) + __expf(v[k].y - m) + __expf(v[k].z - m) + __expf(v[k].w - m);
    s = waveReduceSum(s);
    if (lane == 0){ rowmax[n] = m; rowsum[n] = s; }
}

// ---- per-sample: focal loss terms, a_n, pos_grad scatter, label histogram ----
__global__ void k_sample(const float* __restrict__ cs, const int* __restrict__ label,
                         const float* __restrict__ w, const float* __restrict__ cwb,
                         const float* __restrict__ rowmax, const float* __restrict__ rowsum,
                         float* __restrict__ aN, float* posg, int* counts, float* scal){
    int n = blockIdx.x * blockDim.x + threadIdx.x;
    int l = label[n];
    float m = rowmax[n], s = rowsum[n];
    float x = cs[(size_t)n * C_ + l];
    float logp = x - m - __logf(s);
    float CE = -logp;
    float p = __expf(logp);
    float lossc = (1.f - p) * CE;              // GAMMA = 1
    float t = fminf(fmaxf(cwb[l], 1.f/3.f), 5.f);
    float wn = w[n];
    float pp = p + 1e-5f;                       // softmax + 1e-5 at true class
    float fg = wn * ((1.f - pp) / pp - __logf(pp));
    aN[n] = fg * pp;
    float pg = (1.f - pp) * pp * fg;
    atomicAdd(&posg[l], pg);
    atomicAdd(&counts[l], 1);

    __shared__ float r1[256], r2[256];
    int tid = threadIdx.x;
    r1[tid] = lossc * t * wn; r2[tid] = t;
    __syncthreads();
    for (int o = 128; o > 0; o >>= 1){
        if (tid < o){ r1[tid] += r1[tid + o]; r2[tid] += r2[tid + o]; }
        __syncthreads();
    }
    if (tid == 0){ atomicAdd(&scal[0], r1[0]); atomicAdd(&scal[1], r2[0]); }
}

// ---- exclusive scan of counts -> bucket offsets (+ mutable cursor copy) ----
__global__ void k_scan(const int* __restrict__ counts, int* offsets, int* cursor){
    __shared__ int partial[256];
    int t = threadIdx.x;
    int base = t * 5;
    int local[5]; int s = 0;
    #pragma unroll
    for (int k = 0; k < 5; ++k){
        int idx = base + k;
        int c = (idx < C_) ? counts[idx] : 0;
        local[k] = s; s += c;
    }
    partial[t] = s;
    __syncthreads();
    for (int o = 1; o < 256; o <<= 1){
        int v = 0;
        if (t >= o) v = partial[t - o];
        __syncthreads();
        partial[t] += v;
        __syncthreads();
    }
    int pre = (t > 0) ? partial[t - 1] : 0;
    #pragma unroll
    for (int k = 0; k < 5; ++k){
        int idx = base + k;
        if (idx < C_){ offsets[idx] = pre + local[k]; cursor[idx] = pre + local[k]; }
    }
}

// ---- counting-sort scatter of sample indices into per-class buckets ----
__global__ void k_scatter(const int* __restrict__ label, int* cursor, int* bucket){
    int n = blockIdx.x * blockDim.x + threadIdx.x;
    int l = label[n];
    int pos = atomicAdd(&cursor[l], 1);
    bucket[pos] = n;
}

// ---- per-class corr row, fused with EMA into accu ----
__global__ void k_corr(const float* __restrict__ cs, const int* __restrict__ bucket,
                       const int* __restrict__ counts, const int* __restrict__ offsets,
                       const float* __restrict__ rowmax, const float* __restrict__ rowsum,
                       const float* __restrict__ aN, const float* __restrict__ posg,
                       const float* __restrict__ cga, float* __restrict__ accu, int Nn){
    int i = blockIdx.x;
    int t = threadIdx.x;
    int cnt = counts[i], start = offsets[i];
    float acc0=0.f, acc1=0.f, acc2=0.f, acc3=0.f, acc4=0.f, suma=0.f;
    for (int s = 0; s < cnt; ++s){
        int n = bucket[start + s];
        float m = rowmax[n];
        float a = aN[n];
        float inv = a / rowsum[n];
        suma += a;
        const float* row = cs + (size_t)n * C_;
        acc0 += inv * __expf(row[t       ] - m);
        acc1 += inv * __expf(row[t +  256] - m);
        acc2 += inv * __expf(row[t +  512] - m);
        acc3 += inv * __expf(row[t +  768] - m);
        if (t + 1024 < C_) acc4 += inv * __expf(row[t + 1024] - m);
    }
    float eps = suma * 1e-5f;                 // Σ a_n · 1e-5 (the +1e-5 in prob)
    float scale = 100.f / (float)Nn;
    float diagv = -100.f * posg[i] / (float)Nn;
    const float* cgarow = cga + (size_t)i * C_;
    float* arow = accu + (size_t)i * C_;
    #define WR(J, ACC) { int j=(J); float cgv=((ACC)+eps)*scale; if (j==i) cgv=diagv; \
                         arow[j] = 0.999f*cgarow[j] + 0.001f*cgv; }
    WR(t,        acc0); WR(t +  256, acc1); WR(t +  512, acc2); WR(t +  768, acc3);
    if (t + 1024 < C_) WR(t + 1024, acc4);
    #undef WR
}

// ---- cw2 = softmax(classes_logits) * C ; also written to output slot ----
__global__ void k_cw2(const float* __restrict__ logits, float* cw2, float* out){
    __shared__ float red[256];
    int t = threadIdx.x;
    float x[5]; float m = -3.402823466e38f;
    #pragma unroll
    for (int k = 0; k < 5; ++k){
        int j = t + k * 256;
        x[k] = (j < C_) ? logits[j] : -3.402823466e38f;
        m = fmaxf(m, x[k]);
    }
    red[t] = m; __syncthreads();
    for (int o = 128; o > 0; o >>= 1){ if (t < o) red[t] = fmaxf(red[t], red[t+o]); __syncthreads(); }
    float bm = red[0]; __syncthreads();
    float s = 0.f;
    #pragma unroll
    for (int k = 0; k < 5; ++k){ int j = t + k * 256; if (j < C_) s += __expf(x[k] - bm); }
    red[t] = s; __syncthreads();
    for (int o = 128; o > 0; o >>= 1){ if (t < o) red[t] += red[t+o]; __syncthreads(); }
    float bs = red[0]; __syncthreads();
    #pragma unroll
    for (int k = 0; k < 5; ++k){
        int j = t + k * 256;
        if (j < C_){ float v = __expf(x[k] - bm) / bs * (float)C_; cw2[j] = v; out[2 + j] = v; }
    }
}

// ---- tcol[j] = sum_i cw2[i] * accu[i][j] (2D-chunked + atomics) ----
__global__ void k_matvec(const float* __restrict__ cw2, const float* __restrict__ accu,
                         float* tcol){
    int j = blockIdx.x * 256 + threadIdx.x;
    if (j >= C_) return;
    int i0 = blockIdx.y * 32, i1 = min(i0 + 32, C_);
    float p = 0.f;
    for (int i = i0; i < i1; ++i) p += cw2[i] * accu[(size_t)i * C_ + j];
    atomicAdd(&tcol[j], p);
}

// ---- final: tcw, last-element fixup, clips, logs, the two scalar outputs ----
__global__ void k_final(const float* __restrict__ tcol, const float* __restrict__ accu,
                        const float* __restrict__ cw2, const float* __restrict__ logits,
                        const float* __restrict__ scal, const float* __restrict__ wm0,
                        float* out, int Nn){
    __shared__ float tcw[C_];
    __shared__ float red[256];
    int t = threadIdx.x;
    float psum = 0.f;
    #pragma unroll
    for (int k = 0; k < 5; ++k){
        int j = t + k * 256;
        if (j < C_ - 1){
            float denom = -accu[(size_t)j * C_ + j] + 1e-6f;
            float v = tcol[j] / denom + cw2[j];
            tcw[j] = v; psum += v;           // sum of UNclipped first C-1 values
        }
    }
    red[t] = psum; __syncthreads();
    for (int o = 128; o > 0; o >>= 1){ if (t < o) red[t] += red[t+o]; __syncthreads(); }
    if (t == 0) tcw[C_ - 1] = (float)C_ - red[0];
    __syncthreads();
    float sq = 0.f;
    #pragma unroll
    for (int k = 0; k < 5; ++k){
        int j = t + k * 256;
        if (j < C_){
            float hi = (j == C_ - 1) ? 1.f : 5.f;   // clip(.,1/3,5) then last clip(.,1/3,1)
            float v = fminf(fmaxf(tcw[j], 1.f/3.f), hi);
            float d = logf(v) - logits[j];
            sq += d * d;
        }
    }
    red[t] = sq; __syncthreads();
    for (int o = 128; o > 0; o >>= 1){ if (t < o) red[t] += red[t+o]; __syncthreads(); }
    if (t == 0){
        float wm = 0.999f * wm0[0] + 0.001f * (scal[1] / (float)Nn);
        out[0] = scal[0] / ((float)Nn * wm);   // loss (SELF_LOSS_WEIGHT = 1)
        out[1] = red[0] / (float)C_;           // loss_grad
    }
}

extern "C" void kernel_launch(void* const* d_in, const int* in_sizes, int n_in,
                              void* d_out, int out_size, void* d_ws, size_t ws_size,
                              hipStream_t stream){
    (void)n_in; (void)out_size; (void)ws_size;
    const float* cs     = (const float*)d_in[0];
    const int*   label  = (const int*)  d_in[1];
    const float* weight = (const float*)d_in[2];
    const float* logits = (const float*)d_in[3];
    const float* cwb    = (const float*)d_in[4];
    const float* cga    = (const float*)d_in[5];
    const float* wm0    = (const float*)d_in[6];
    float* out = (float*)d_out;
    const int N = in_sizes[1];                 // 16384

    // workspace layout (float elements)
    float* ws      = (float*)d_ws;
    float* rowmax  = ws;                       // N
    float* rowsum  = ws + N;                   // N
    float* aN      = ws + 2 * N;               // N
    int*   bucket  = (int*)(ws + 3 * N);       // N
    int*   counts  = (int*)(ws + 4 * N);       // C
    int*   offsets = counts + C_;              // C
    int*   cursor  = offsets + C_;             // C
    float* posg    = (float*)(cursor + C_);    // C
    float* cw2     = posg + C_;                // C
    float* tcol    = cw2 + C_;                 // C
    float* scal    = tcol + C_;                // 8
    float* accu    = scal + 8;                 // C*C  (~5.8 MB)

    k_init    <<<(C_ + 255) / 256, 256, 0, stream>>>(posg, counts, tcol, scal);
    k_rowstats<<<N / 4,            256, 0, stream>>>(cs, rowmax, rowsum);
    k_sample  <<<N / 256,          256, 0, stream>>>(cs, label, weight, cwb, rowmax, rowsum,
                                                     aN, posg, counts, scal);
    k_scan    <<<1,                256, 0, stream>>>(counts, offsets, cursor);
    k_scatter <<<N / 256,          256, 0, stream>>>(label, cursor, bucket);
    k_corr    <<<C_,               256, 0, stream>>>(cs, bucket, counts, offsets, rowmax, rowsum,
                                                     aN, posg, cga, accu, N);
    k_cw2     <<<1,                256, 0, stream>>>(logits, cw2, out);
    dim3 g4((C_ + 255) / 256, (C_ + 31) / 32);
    k_matvec  <<<g4,               256, 0, stream>>>(cw2, accu, tcol);
    k_final   <<<1,                256, 0, stream>>>(tcol, accu, cw2, logits, scal, wm0, out, N);
}